// Round 1
// baseline (680.481 us; speedup 1.0000x reference)
//
#include <hip/hip_runtime.h>

#define CN 2000
#define DF 2048
#define NS 20000
#define MAXM 256

typedef __attribute__((ext_vector_type(4))) float          f32x4;
typedef __attribute__((ext_vector_type(4))) int            i32x4;
typedef __attribute__((ext_vector_type(4))) unsigned short u16x4;

__device__ __forceinline__ float wredSum(float v){
#pragma unroll
  for (int o = 32; o >= 1; o >>= 1) v += __shfl_xor(v, o, 64);
  return v;
}
__device__ __forceinline__ float wredMax(float v){
#pragma unroll
  for (int o = 32; o >= 1; o >>= 1) v = fmaxf(v, __shfl_xor(v, o, 64));
  return v;
}
__device__ __forceinline__ unsigned short bfbits(float x){
  union { float f; unsigned u; } c; c.f = x;
  return (unsigned short)((c.u + 0x7fffu + ((c.u >> 16) & 1u)) >> 16);
}

__global__ void k_zero(int* p, int n){
  int i = blockIdx.x * 256 + threadIdx.x;
  if (i < n) p[i] = 0;
}

__global__ void k_hist(const int* __restrict__ rgb, const int* __restrict__ iri,
                       int* cv, int* ci){
  int i = blockIdx.x * 256 + threadIdx.x;
  if (i < NS) atomicAdd(&cv[rgb[i]], 1);
  else if (i < 2 * NS) atomicAdd(&ci[iri[i - NS]], 1);
}

__global__ __launch_bounds__(1024) void k_scan(const int* __restrict__ cv, const int* __restrict__ ci,
                                               int* ov, int* oi){
  __shared__ int s[2048];
  int t = threadIdx.x;
  for (int pass = 0; pass < 2; ++pass){
    const int* c = pass ? ci : cv;
    int* o = pass ? oi : ov;
    s[t] = (t < CN) ? c[t] : 0;
    s[t + 1024] = (t + 1024 < CN) ? c[t + 1024] : 0;
    __syncthreads();
    for (int off = 1; off < 2048; off <<= 1){
      int a = (t >= off) ? s[t - off] : 0;
      int b = (t + 1024 >= off) ? s[t + 1024 - off] : 0;
      __syncthreads();
      s[t] += a; s[t + 1024] += b;
      __syncthreads();
    }
    if (t < CN) o[t] = s[t] - c[t];
    if (t + 1024 < CN) o[t + 1024] = s[t + 1024] - c[t + 1024];
    __syncthreads();
  }
}

__global__ void k_scatter(const int* __restrict__ rgb, const int* __restrict__ iri,
                          const int* __restrict__ ov, const int* __restrict__ oi,
                          int* curv, int* curi, int* ordv, int* ordi){
  int i = blockIdx.x * 256 + threadIdx.x;
  if (i < NS){
    int l = rgb[i];
    int p = atomicAdd(&curv[l], 1);
    ordv[ov[l] + p] = i;
  } else if (i < 2 * NS){
    int k = i - NS;
    int l = iri[k];
    int p = atomicAdd(&curi[l], 1);
    ordi[oi[l] + p] = k;
  }
}

// One block per (modality,class): softmax each member sample's logits row,
// accumulate mean in LDS -> proto row, entropy.
__global__ __launch_bounds__(256) void k_class(const float* __restrict__ visl, const float* __restrict__ irl,
    const int* __restrict__ cv, const int* __restrict__ ci,
    const int* __restrict__ ov, const int* __restrict__ oi,
    const int* __restrict__ ordv, const int* __restrict__ ordi,
    float* __restrict__ pv, float* __restrict__ pi,
    float* __restrict__ ev, float* __restrict__ ei){
  __shared__ float acc[2048];
  __shared__ int mem[MAXM];
  __shared__ float red[4];
  int t = threadIdx.x;
  bool ir = (blockIdx.x >= CN);
  int c = ir ? blockIdx.x - CN : blockIdx.x;
  const float* logits = ir ? irl : visl;
  int n = (ir ? ci : cv)[c];
  int base = (ir ? oi : ov)[c];
  const int* ord = ir ? ordi : ordv;
  float* proto = ir ? pi : pv;
  float* ent = ir ? ei : ev;
  bool useL = (n <= MAXM);
  for (int m = t; m < n && m < MAXM; m += 256) mem[m] = ord[base + m];
  for (int j = t; j < 2048; j += 256) acc[j] = 0.f;
  __syncthreads();
  if (t == 0 && useL){  // deterministic member order across replays
    for (int a = 1; a < n; ++a){
      int key = mem[a]; int b = a - 1;
      while (b >= 0 && mem[b] > key){ mem[b + 1] = mem[b]; --b; }
      mem[b + 1] = key;
    }
  }
  __syncthreads();
  for (int m = 0; m < n; ++m){
    int sidx = useL ? mem[m] : ord[base + m];
    const float* row = logits + (size_t)sidx * CN;
    float x[8]; float mx = -3.0e38f;
#pragma unroll
    for (int k = 0; k < 8; ++k){
      int j = t + k * 256;
      float v = (j < CN) ? row[j] : -3.0e38f;
      x[k] = v; mx = fmaxf(mx, v);
    }
    mx = wredMax(mx);
    if ((t & 63) == 0) red[t >> 6] = mx;
    __syncthreads();
    mx = fmaxf(fmaxf(red[0], red[1]), fmaxf(red[2], red[3]));
    __syncthreads();
    float sm = 0.f;
#pragma unroll
    for (int k = 0; k < 8; ++k){
      int j = t + k * 256;
      float e = (j < CN) ? expf(x[k] - mx) : 0.f;
      x[k] = e; sm += e;
    }
    sm = wredSum(sm);
    if ((t & 63) == 0) red[t >> 6] = sm;
    __syncthreads();
    sm = red[0] + red[1] + red[2] + red[3];
    float inv = 1.f / sm;
#pragma unroll
    for (int k = 0; k < 8; ++k){
      int j = t + k * 256;
      if (j < CN) acc[j] += x[k] * inv;
    }
    __syncthreads();
  }
  float invc = 1.f / fmaxf((float)n, 1.f);
  float el = 0.f;
#pragma unroll
  for (int k = 0; k < 8; ++k){
    int j = t + k * 256;
    if (j < CN){
      float p = acc[j] * invc;
      proto[(size_t)c * CN + j] = p;
      p = fmaxf(p, 1e-12f);
      el -= p * logf(p);
    }
  }
  el = wredSum(el);
  if ((t & 63) == 0) red[t >> 6] = el;
  __syncthreads();
  if (t == 0) ent[c] = red[0] + red[1] + red[2] + red[3];
}

__global__ __launch_bounds__(256) void k_rnorm(const float* __restrict__ vm, const float* __restrict__ im,
                                               float* rv, float* ri){
  int g = blockIdx.x * 256 + threadIdx.x;
  int w = g >> 6, l = g & 63;
  if (w >= 2 * CN) return;
  const float* src = (w < CN) ? vm : im;
  int r = (w < CN) ? w : w - CN;
  const f32x4* row = (const f32x4*)(src + (size_t)r * DF);
  float s = 0.f;
#pragma unroll
  for (int k = 0; k < 8; ++k){
    f32x4 v = row[l + k * 64];
    s += v[0]*v[0] + v[1]*v[1] + v[2]*v[2] + v[3]*v[3];
  }
  s = wredSum(s);
  if (l == 0){
    float* dst = (w < CN) ? rv : ri;
    dst[r] = 1.f / fmaxf(sqrtf(s), 1e-12f);
  }
}

// 128x128 tile bf16 MFMA GEMM over K=2048; epilogue builds K = exp(-cost/reg)*mask
// and writes both K (row-major) and K^T.
__global__ __launch_bounds__(256) void k_gemm(const float* __restrict__ vm, const float* __restrict__ im,
    const float* __restrict__ pv, const float* __restrict__ pi,
    const float* __restrict__ ev, const float* __restrict__ ei,
    const float* __restrict__ rv, const float* __restrict__ ri,
    const int* __restrict__ cv, const int* __restrict__ ci,
    float* __restrict__ Km, float* __restrict__ KTm){
  __shared__ unsigned short Ab[128 * 32];
  __shared__ unsigned short Bb[128 * 32];
  int t = threadIdx.x;
  int i0 = blockIdx.y * 128;
  int j0 = blockIdx.x * 128;
  int w = t >> 6, l = t & 63;
  int wm = w >> 1, wn = w & 1;
  f32x4 z = {0.f, 0.f, 0.f, 0.f};
  f32x4 acc[4][4];
#pragma unroll
  for (int a = 0; a < 4; ++a)
#pragma unroll
    for (int b = 0; b < 4; ++b) acc[a][b] = z;

  for (int kt = 0; kt < DF / 32; ++kt){
    int k0 = kt * 32;
#pragma unroll
    for (int it = 0; it < 4; ++it){
      int idx = t + it * 256;
      int row = idx >> 3, c4 = idx & 7;
      f32x4 va = z;
      int gr = i0 + row;
      if (gr < CN) va = *(const f32x4*)(vm + (size_t)gr * DF + k0 + c4 * 4);
      u16x4 wa;
      wa[0] = bfbits(va[0]); wa[1] = bfbits(va[1]); wa[2] = bfbits(va[2]); wa[3] = bfbits(va[3]);
      *(u16x4*)&Ab[row * 32 + c4 * 4] = wa;
      f32x4 vb = z;
      int gc = j0 + row;
      if (gc < CN) vb = *(const f32x4*)(im + (size_t)gc * DF + k0 + c4 * 4);
      u16x4 wb;
      wb[0] = bfbits(vb[0]); wb[1] = bfbits(vb[1]); wb[2] = bfbits(vb[2]); wb[3] = bfbits(vb[3]);
      *(u16x4*)&Bb[row * 32 + c4 * 4] = wb;
    }
    __syncthreads();
    i32x4 af[4], bfr[4];
    int lr = l & 15, lk = (l >> 4) * 8;
#pragma unroll
    for (int f = 0; f < 4; ++f){
      af[f]  = *(const i32x4*)&Ab[(wm * 64 + f * 16 + lr) * 32 + lk];
      bfr[f] = *(const i32x4*)&Bb[(wn * 64 + f * 16 + lr) * 32 + lk];
    }
#pragma unroll
    for (int a = 0; a < 4; ++a)
#pragma unroll
      for (int b = 0; b < 4; ++b)
        asm volatile("v_mfma_f32_16x16x32_bf16 %0, %1, %2, %0"
                     : "+v"(acc[a][b]) : "v"(af[a]), "v"(bfr[b]));
    __syncthreads();
  }

#pragma unroll
  for (int a = 0; a < 4; ++a){
    int ibase = i0 + wm * 64 + a * 16 + ((l >> 4) << 2);
#pragma unroll
    for (int b = 0; b < 4; ++b){
      int j = j0 + wn * 64 + b * 16 + (l & 15);
      if (j < CN){
#pragma unroll
        for (int r = 0; r < 4; ++r){
          int i = ibase + r;
          if (i < CN){
            float dot = acc[a][b][r] * rv[i] * ri[j];
            float feat = fminf(fmaxf((dot + 1.f) * 0.5f, 0.f), 1.f);
            float pred = 0.5f * (pv[(size_t)i * CN + j] + pi[(size_t)j * CN + i]);
            float conf = fminf(fmaxf(1.f - (ev[i] + ei[j]) / 15.201804919084164f, 0.f), 1.f);
            float cost = 0.45f * (1.f - pred) + 0.4f * (1.f - feat) + 0.15f * (1.f - conf);
            float kv = ((cv[i] > 0) && (ci[j] > 0)) ? expf(-cost / 0.07f) : 0.f;
            Km[(size_t)i * CN + j]  = kv;
            KTm[(size_t)j * CN + i] = kv;
          }
        }
      }
    }
  }
}

__global__ void k_ones(float* u, float* v){
  int i = blockIdx.x * 256 + threadIdx.x;
  if (i < CN){ u[i] = 1.f; v[i] = 1.f; }
}

// out[i] = a_i > 0 ? a_i / (dot(M[i], x) + 1e-8) : 0,  a_i = cnt[i]/20000
__global__ __launch_bounds__(256) void k_matvec(const float* __restrict__ M, const float* __restrict__ x,
    const int* __restrict__ cnt, float* __restrict__ out){
  int g = blockIdx.x * 256 + threadIdx.x;
  int wid = g >> 6, l = g & 63;
  if (wid >= CN) return;
  const f32x4* row = (const f32x4*)(M + (size_t)wid * CN);
  const f32x4* xv = (const f32x4*)x;
  float s = 0.f;
#pragma unroll
  for (int k = 0; k < 8; ++k){
    int idx = l + k * 64;
    if (idx < CN / 4){
      f32x4 m = row[idx], q = xv[idx];
      s += m[0]*q[0] + m[1]*q[1] + m[2]*q[2] + m[3]*q[3];
    }
  }
  s = wredSum(s);
  if (l == 0){
    float a = (float)cnt[wid] / 20000.0f;
    out[wid] = (a > 0.f) ? a / (s + 1e-8f) : 0.f;
  }
}

__global__ __launch_bounds__(256) void k_fsums(const float* __restrict__ Km, const float* __restrict__ KTm,
    const float* __restrict__ u, const float* __restrict__ v,
    float* __restrict__ rsi, float* __restrict__ csi){
  int g = blockIdx.x * 256 + threadIdx.x;
  int wid = g >> 6, l = g & 63;
  if (wid >= 2 * CN) return;
  bool col = (wid >= CN);
  int r = col ? wid - CN : wid;
  const float* M = col ? KTm : Km;
  const float* xx = col ? u : v;
  const f32x4* row = (const f32x4*)(M + (size_t)r * CN);
  const f32x4* xv = (const f32x4*)xx;
  float s = 0.f;
#pragma unroll
  for (int k = 0; k < 8; ++k){
    int idx = l + k * 64;
    if (idx < CN / 4){
      f32x4 m = row[idx], q = xv[idx];
      s += m[0]*q[0] + m[1]*q[1] + m[2]*q[2] + m[3]*q[3];
    }
  }
  s = wredSum(s);
  if (l == 0){
    float scale = col ? v[r] : u[r];
    float* dst = col ? csi : rsi;
    dst[r] = 1.f / fmaxf(scale * s, 1e-12f);
  }
}

// In-place: row_t[i][j] = u_i*K[i][j]*v_j*rsinv_i, plus per-row max/argmax.
__global__ __launch_bounds__(256) void k_rowt(const float* M, const float* __restrict__ u,
    const float* __restrict__ v, const float* __restrict__ rsi,
    float* outm, float* __restrict__ conf, int* __restrict__ assign){
  __shared__ float rvv[4]; __shared__ int rii[4];
  int i = blockIdx.x, t = threadIdx.x;
  float f = u[i] * rsi[i];
  float bm = -1.f; int bi = 1 << 30;
#pragma unroll
  for (int k = 0; k < 8; ++k){
    int j = t + k * 256;
    if (j < CN){
      float val = f * M[(size_t)i * CN + j] * v[j];
      outm[(size_t)i * CN + j] = val;
      if (val > bm){ bm = val; bi = j; }   // j ascending -> first max kept
    }
  }
  for (int o = 32; o >= 1; o >>= 1){
    float om = __shfl_xor(bm, o, 64);
    int oi2 = __shfl_xor(bi, o, 64);
    if (om > bm || (om == bm && oi2 < bi)){ bm = om; bi = oi2; }
  }
  if ((t & 63) == 0){ rvv[t >> 6] = bm; rii[t >> 6] = bi; }
  __syncthreads();
  if (t == 0){
    for (int q = 1; q < 4; ++q){
      if (rvv[q] > bm || (rvv[q] == bm && rii[q] < bi)){ bm = rvv[q]; bi = rii[q]; }
    }
    conf[i] = bm;
    assign[i] = bi;
  }
}

__global__ void k_flags(const int* __restrict__ cv, const int* __restrict__ ci,
    const float* __restrict__ rc, const float* __restrict__ cc,
    const int* __restrict__ ra, const int* __restrict__ ca,
    int* fcom, int* fspec, int* fremr, int* fremc){
  int i = blockIdx.x * 256 + threadIdx.x;
  if (i >= CN) return;
  bool av = cv[i] > 0, ai = ci[i] > 0;
  float r = rc[i];
  bool mr = (ca[ra[i]] == i);
  bool common = av && (r >= 0.55f) && mr;
  bool spec = av && (r >= 0.55f) && !common;
  bool remr = av && (r >= 0.25f) && (r < 0.55f);
  float cf = cc[i];
  bool remc = ai && (cf >= 0.25f) && (cf < 0.55f);
  fcom[i] = common ? 1 : 0;
  fspec[i] = spec ? 1 : 0;
  fremr[i] = remr ? 1 : 0;
  fremc[i] = remc ? 1 : 0;
}

__global__ __launch_bounds__(256) void k_fill(const float* __restrict__ rt,
    const int* __restrict__ fcom, const int* __restrict__ fspec,
    const float* __restrict__ rc, const int* __restrict__ ra,
    float* o2, float* o3, float* o4, float* o5){
  int i = blockIdx.x, t = threadIdx.x;
  int cm = fcom[i], sp = fspec[i];
  float cval = rc[i]; int aidx = ra[i];
#pragma unroll
  for (int k = 0; k < 8; ++k){
    int j = t + k * 256;
    if (j < CN){
      size_t off = (size_t)i * CN + j;
      o2[off] = (cm && (j == aidx)) ? cval : 0.f;
      o3[off] = sp ? rt[off] : 0.f;
      o4[off] = 0.f;
      o5[off] = 0.f;
    }
  }
}

__global__ __launch_bounds__(256) void k_topk(const float* __restrict__ rt, const float* __restrict__ ct,
    const int* __restrict__ fremr, const int* __restrict__ fremc,
    float* o4, float* o5){
  __shared__ float sv[256 * 3];
  __shared__ int si[256 * 3];
  int b = blockIdx.x;
  bool colp = (b >= CN);
  int r = colp ? b - CN : b;
  if (!(colp ? fremc[r] : fremr[r])) return;
  const float* M = colp ? ct : rt;
  float* o = colp ? o5 : o4;
  int t = threadIdx.x;
  float v0 = -1.f, v1 = -1.f, v2 = -1.f;
  int i0 = 1 << 30, i1 = 1 << 30, i2 = 1 << 30;
  for (int k = 0; k < 8; ++k){
    int j = t + k * 256;
    if (j >= CN) break;
    float val = M[(size_t)r * CN + j];
    if (val > v0 || (val == v0 && j < i0)){ v2=v1; i2=i1; v1=v0; i1=i0; v0=val; i0=j; }
    else if (val > v1 || (val == v1 && j < i1)){ v2=v1; i2=i1; v1=val; i1=j; }
    else if (val > v2 || (val == v2 && j < i2)){ v2=val; i2=j; }
  }
  sv[t*3+0]=v0; sv[t*3+1]=v1; sv[t*3+2]=v2;
  si[t*3+0]=i0; si[t*3+1]=i1; si[t*3+2]=i2;
  __syncthreads();
  if (t == 0){
    float w0=-1.f, w1=-1.f, w2=-1.f; int j0=1<<30, j1=1<<30, j2=1<<30;
    for (int q = 0; q < 256 * 3; ++q){
      float val = sv[q]; int j = si[q];
      if (j >= CN) continue;
      if (val > w0 || (val == w0 && j < j0)){ w2=w1; j2=j1; w1=w0; j1=j0; w0=val; j0=j; }
      else if (val > w1 || (val == w1 && j < j1)){ w2=w1; j2=j1; w1=val; j1=j; }
      else if (val > w2 || (val == w2 && j < j2)){ w2=val; j2=j; }
    }
    o[(size_t)r * CN + j0] = w0;
    o[(size_t)r * CN + j1] = w1;
    o[(size_t)r * CN + j2] = w2;
  }
}

extern "C" void kernel_launch(void* const* d_in, const int* in_sizes, int n_in,
                              void* d_out, int out_size, void* d_ws, size_t ws_size,
                              hipStream_t stream){
  (void)in_sizes; (void)n_in; (void)out_size; (void)ws_size;
  const float* visl = (const float*)d_in[0];
  const float* irl  = (const float*)d_in[1];
  const float* vm   = (const float*)d_in[2];
  const float* im   = (const float*)d_in[3];
  const int* rgb    = (const int*)d_in[4];
  const int* iri    = (const int*)d_in[5];
  float* out = (float*)d_out;
  float* o0 = out;                 // K  -> row_t (in place)
  float* o1 = out + 4000000;       // K^T-> col_t (in place)
  float* o2 = out + 8000000;       // proto_v -> common_rm
  float* o3 = out + 12000000;      // proto_i -> specific_rm
  float* o4 = out + 16000000;      // remain_rm
  float* o5 = out + 20000000;      // remain_col_rm
  char* sm = (char*)d_ws;          // ~340 KB of small arrays
  float* ev   = (float*)(sm + 0);
  float* ei   = (float*)(sm + 8000);
  float* rv   = (float*)(sm + 16000);
  float* ri   = (float*)(sm + 24000);
  float* uvec = (float*)(sm + 32000);
  float* vvec = (float*)(sm + 40000);
  float* rsi  = (float*)(sm + 48000);
  float* csi  = (float*)(sm + 56000);
  float* rconf= (float*)(sm + 64000);
  float* cconf= (float*)(sm + 72000);
  int* rass = (int*)(sm + 80000);
  int* cass = (int*)(sm + 88000);
  int* cv   = (int*)(sm + 96000);
  int* ci   = (int*)(sm + 104000);
  int* ov   = (int*)(sm + 112000);
  int* oi   = (int*)(sm + 120000);
  int* curv = (int*)(sm + 128000);
  int* curi = (int*)(sm + 136000);
  int* fcom = (int*)(sm + 144000);
  int* fspec= (int*)(sm + 152000);
  int* fremr= (int*)(sm + 160000);
  int* fremc= (int*)(sm + 168000);
  int* ordv = (int*)(sm + 176000);
  int* ordi = (int*)(sm + 256000);

  k_zero<<<47, 256, 0, stream>>>(cv, 12000);   // cv,ci,ov,oi,curv,curi contiguous
  k_hist<<<157, 256, 0, stream>>>(rgb, iri, cv, ci);
  k_scan<<<1, 1024, 0, stream>>>(cv, ci, ov, oi);
  k_scatter<<<157, 256, 0, stream>>>(rgb, iri, ov, oi, curv, curi, ordv, ordi);
  k_class<<<2 * CN, 256, 0, stream>>>(visl, irl, cv, ci, ov, oi, ordv, ordi, o2, o3, ev, ei);
  k_rnorm<<<1000, 256, 0, stream>>>(vm, im, rv, ri);
  dim3 gg(16, 16);
  k_gemm<<<gg, 256, 0, stream>>>(vm, im, o2, o3, ev, ei, rv, ri, cv, ci, o0, o1);
  k_ones<<<8, 256, 0, stream>>>(uvec, vvec);
  for (int it = 0; it < 30; ++it){
    k_matvec<<<500, 256, 0, stream>>>(o0, vvec, cv, uvec);
    k_matvec<<<500, 256, 0, stream>>>(o1, uvec, ci, vvec);
  }
  k_fsums<<<1000, 256, 0, stream>>>(o0, o1, uvec, vvec, rsi, csi);
  k_rowt<<<CN, 256, 0, stream>>>(o0, uvec, vvec, rsi, o0, rconf, rass);
  k_rowt<<<CN, 256, 0, stream>>>(o1, vvec, uvec, csi, o1, cconf, cass);
  k_flags<<<8, 256, 0, stream>>>(cv, ci, rconf, cconf, rass, cass, fcom, fspec, fremr, fremc);
  k_fill<<<CN, 256, 0, stream>>>(o0, fcom, fspec, rconf, rass, o2, o3, o4, o5);
  k_topk<<<2 * CN, 256, 0, stream>>>(o0, o1, fremr, fremc, o4, o5);
}